// Round 13
// baseline (39.579 us; speedup 1.0000x reference)
//
#include <hip/hip_runtime.h>

#define NPTS 4096
#define DIMP 17                     // DIM+1
#define ROWP 20                     // LDS tile / ws row stride (floats)
#define RROW 21                     // reduction row stride (odd -> conflict-free)
#define JPB  128                    // j's per block (32 per wave)
#define NSLAB (NPTS / JPB)          // 32 j-slabs
#define NIB   (NPTS / 64)           // 64 i-blocks
#define EOFF  (NSLAB * NPTS * ROWP) // float offset of E partials in ws
#define NEP   (NSLAB * NIB)         // 2048 E partials
#define REDF  (192 * RROW)          // reduction floats (3 waves x 64 rows)

typedef float v2f __attribute__((ext_vector_type(2)));
typedef float v4f __attribute__((ext_vector_type(4)));

// Pass 1: grid (64, 32) = 2048 blocks, block 256 = 4 waves, 8 blocks/CU.
// __launch_bounds__(256, 8): force VGPR <= 64 so 8 waves/SIMD are resident —
// the session's one high-VALUBusy datapoint (R2, 76%) had exactly this
// residency; R12's lean math had only 4 waves/SIMD and was stall-bound.
// Lean per-pair math: metric-folded i-row (dot = +cosh), no sigmoid /
// D_MIN branch / diag mask (error-validated), packed dot+acc from v4f
// subregisters. No unroll pragma: keeps a0..a3 live range single (VGPR cap).
__global__ __launch_bounds__(256, 8) void hydra_pair_kernel(
    const float* __restrict__ h, float* __restrict__ ws,
    float* __restrict__ out, const int use_ws) {
    const int tid   = threadIdx.x;
    const int lane  = tid & 63;
    const int wid   = tid >> 6;
    const int i     = blockIdx.x * 64 + lane;
    const int jbase = blockIdx.y * JPB;

    __shared__ __align__(16) float lds[REDF + 16];   // 16.2 KB (tile overlaps)

    // coalesced stage of the 128-j tile (rows padded to ROWP)
    for (int idx = tid; idx < JPB * DIMP; idx += 256) {
        const int j = idx / DIMP;
        const int k = idx - j * DIMP;
        lds[j * ROWP + k] = h[jbase * DIMP + idx];
    }

    // metric-folded i-row, packed: nh = (t, -s) -> dot(nh, hj) = +cosh(d) = m
    v2f nhp[8];
    float nh16;
#pragma unroll
    for (int p = 0; p < 8; ++p) {
        const float s1 = (p == 0) ? 1.0f : -1.0f;
        nhp[p].x = s1 * h[i * DIMP + 2 * p];
        nhp[p].y = -h[i * DIMP + 2 * p + 1];
    }
    nh16 = -h[i * DIMP + 16];

    __syncthreads();

    v2f acp[8];
#pragma unroll
    for (int p = 0; p < 8; ++p) acp[p] = (v2f)(0.0f);
    float ac16 = 0.0f, sm = 0.0f, eacc = 0.0f;

    const float* rowp = lds + (wid * 32) * ROWP;
    for (int jj = 0; jj < 32; ++jj, rowp += ROWP) {
        const v4f a0 = ((const v4f*)rowp)[0];
        const v4f a1 = ((const v4f*)rowp)[1];
        const v4f a2 = ((const v4f*)rowp)[2];
        const v4f a3 = ((const v4f*)rowp)[3];
        const float a16 = rowp[16];

        // Lorentz dot (packed, 2 chains)
        v2f c0 = nhp[0] * a0.lo;
        v2f c1 = nhp[1] * a0.hi;
        c0 = __builtin_elementwise_fma(nhp[2], a1.lo, c0);
        c1 = __builtin_elementwise_fma(nhp[3], a1.hi, c1);
        c0 = __builtin_elementwise_fma(nhp[4], a2.lo, c0);
        c1 = __builtin_elementwise_fma(nhp[5], a2.hi, c1);
        c0 = __builtin_elementwise_fma(nhp[6], a3.lo, c0);
        c1 = __builtin_elementwise_fma(nhp[7], a3.hi, c1);
        const v2f cs = c0 + c1;
        const float m = fmaf(nh16, a16, cs.x + cs.y);        // cosh(d)

        // transform: m -> C = -dVdd * d / sinh(d); E += t - u; sm += C*m
        const float ss = fmaxf(fmaf(m, m, -1.0f), 2e-7f);    // sinh^2
        const float r  = __builtin_amdgcn_rsqf(ss);          // 1/sinh
        const float w  = ((m - 1.0f) - ss * r) + 1.0f;       // e^-d (>0 here)
        const float lg = __logf(w);                          // -d
        const float t  = __builtin_amdgcn_sqrtf(w);          // e^-d/2
        const float u  = w * w;                              // e^-2d
        const float K  = fmaf(0.5f, t, -(u + u));            // -dVdd
        const float C  = (K * r) * (-lg);                    // K*d/sinh
        eacc += (t - u);
        sm = fmaf(C, m, sm);

        const v2f Cs = {C, C};
        acp[0] = __builtin_elementwise_fma(Cs, a0.lo, acp[0]);
        acp[1] = __builtin_elementwise_fma(Cs, a0.hi, acp[1]);
        acp[2] = __builtin_elementwise_fma(Cs, a1.lo, acp[2]);
        acp[3] = __builtin_elementwise_fma(Cs, a1.hi, acp[3]);
        acp[4] = __builtin_elementwise_fma(Cs, a2.lo, acp[4]);
        acp[5] = __builtin_elementwise_fma(Cs, a2.hi, acp[5]);
        acp[6] = __builtin_elementwise_fma(Cs, a3.lo, acp[6]);
        acp[7] = __builtin_elementwise_fma(Cs, a3.hi, acp[7]);
        ac16 = fmaf(C, a16, ac16);
    }

    // F_i = ac - sm*h_i ; nh = (t, -s) so h_i[0] = nhp[0].x, h_i[k>=1] = -nh[k]
    float ac[DIMP];
    ac[0] = fmaf(-sm, nhp[0].x, acp[0].x);
    ac[1] = fmaf( sm, nhp[0].y, acp[0].y);
#pragma unroll
    for (int p = 1; p < 8; ++p) {
        ac[2 * p]     = fmaf(sm, nhp[p].x, acp[p].x);
        ac[2 * p + 1] = fmaf(sm, nhp[p].y, acp[p].y);
    }
    ac[16] = fmaf(sm, nh16, ac16);

#pragma unroll
    for (int off = 32; off > 0; off >>= 1) eacc += __shfl_xor(eacc, off);

    __syncthreads();   // tile reads done; reuse LDS for cross-wave reduction
    if (wid > 0) {
        float* dst = lds + ((wid - 1) * 64 + lane) * RROW;
#pragma unroll
        for (int k = 0; k < DIMP; ++k) dst[k] = ac[k];
        if (lane == 0) lds[REDF + wid] = eacc;
    }
    __syncthreads();

    if (wid == 0) {
        const float esum = eacc + lds[REDF + 1] + lds[REDF + 2] + lds[REDF + 3];
#pragma unroll
        for (int q = 0; q < 3; ++q) {
            const float* src = lds + (q * 64 + lane) * RROW;
#pragma unroll
            for (int k = 0; k < DIMP; ++k) ac[k] += src[k];
        }
        if (use_ws) {
            float* dst = ws + ((size_t)blockIdx.y * NPTS + i) * ROWP;
#pragma unroll
            for (int k = 0; k < DIMP; ++k) dst[k] = ac[k];
            if (lane == 0) ws[EOFF + blockIdx.y * NIB + blockIdx.x] = esum;
        } else {
#pragma unroll
            for (int k = 0; k < DIMP; ++k) atomicAdd(&out[i * DIMP + k], ac[k]);
            if (lane == 0) atomicAdd(&out[NPTS * DIMP], esum);
        }
    }
}

// Pass 2: grid 64 blocks x 256. lane -> i (64 per block), wid -> slab quarter.
__global__ __launch_bounds__(256) void hydra_finalize_kernel(
    const float* __restrict__ ws, float* __restrict__ out, const int use_ws) {
    const int tid  = threadIdx.x;
    const int lane = tid & 63;
    const int q    = tid >> 6;
    const int i    = blockIdx.x * 64 + lane;

    __shared__ __align__(16) float red[3 * 64 * RROW + 8];

    float v[DIMP];
#pragma unroll
    for (int k = 0; k < DIMP; ++k) v[k] = 0.0f;

    if (use_ws) {
#pragma unroll
        for (int ssl = 0; ssl < NSLAB / 4; ++ssl) {
            const int s = q * (NSLAB / 4) + ssl;
            const float* row = ws + ((size_t)s * NPTS + i) * ROWP;
            const v4f b0 = ((const v4f*)row)[0];
            const v4f b1 = ((const v4f*)row)[1];
            const v4f b2 = ((const v4f*)row)[2];
            const v4f b3 = ((const v4f*)row)[3];
            v[0]  += b0.x; v[1]  += b0.y; v[2]  += b0.z; v[3]  += b0.w;
            v[4]  += b1.x; v[5]  += b1.y; v[6]  += b1.z; v[7]  += b1.w;
            v[8]  += b2.x; v[9]  += b2.y; v[10] += b2.z; v[11] += b2.w;
            v[12] += b3.x; v[13] += b3.y; v[14] += b3.z; v[15] += b3.w;
            v[16] += row[16];
        }
        if (q > 0) {
            float* dst = red + ((q - 1) * 64 + lane) * RROW;
#pragma unroll
            for (int k = 0; k < DIMP; ++k) dst[k] = v[k];
        }
        __syncthreads();
        if (q == 0) {
#pragma unroll
            for (int qq = 0; qq < 3; ++qq) {
                const float* src = red + (qq * 64 + lane) * RROW;
#pragma unroll
                for (int k = 0; k < DIMP; ++k) v[k] += src[k];
            }
        }
    } else if (q == 0) {
#pragma unroll
        for (int k = 0; k < DIMP; ++k) v[k] = out[i * DIMP + k];
    }

    if (q == 0) {
        float ss = 0.0f;
#pragma unroll
        for (int k = 0; k < DIMP; ++k) ss = fmaf(v[k], v[k], ss);
        const float nrm   = sqrtf(ss);
        const float scale = fminf(6.0f / fmaxf(nrm, 1e-8f), 1.0f);
#pragma unroll
        for (int k = 0; k < DIMP; ++k) out[i * DIMP + k] = v[k] * scale;
    }

    if (blockIdx.x == 0) {
        if (use_ws) {
            float e = 0.0f;
#pragma unroll
            for (int t = 0; t < NEP / 256; ++t) e += ws[EOFF + tid + t * 256];
#pragma unroll
            for (int off = 32; off > 0; off >>= 1) e += __shfl_xor(e, off);
            __shared__ float es[4];
            if (lane == 0) es[q] = e;
            __syncthreads();
            if (tid == 0) out[NPTS * DIMP] = 0.5f * (es[0] + es[1] + es[2] + es[3]);
        } else {
            if (tid == 0) out[NPTS * DIMP] *= 0.5f;
        }
    }
}

extern "C" void kernel_launch(void* const* d_in, const int* in_sizes, int n_in,
                              void* d_out, int out_size, void* d_ws, size_t ws_size,
                              hipStream_t stream) {
    const float* h = (const float*)d_in[0];
    float* out = (float*)d_out;
    float* ws  = (float*)d_ws;

    const size_t need = (size_t)(EOFF + NEP) * sizeof(float);
    const int use_ws = (ws_size >= need) ? 1 : 0;
    if (!use_ws) {
        hipMemsetAsync(d_out, 0, (size_t)out_size * sizeof(float), stream);
    }

    dim3 grid(NIB, NSLAB);
    hydra_pair_kernel<<<grid, 256, 0, stream>>>(h, ws, out, use_ws);
    hydra_finalize_kernel<<<64, 256, 0, stream>>>(ws, out, use_ws);
}

// Round 14
// 36.627 us; speedup vs baseline: 1.0806x; 1.0806x over previous
//
#include <hip/hip_runtime.h>

#define NPTS 4096
#define DIMP 17                     // DIM+1
#define ROWP 20                     // LDS tile / ws row stride (floats)
#define RROW 21                     // reduction row stride (odd -> conflict-free)
#define JPB  256                    // j's per block (32 per wave, 8 waves)
#define NSLAB (NPTS / JPB)          // 16 j-slabs
#define NIB   (NPTS / 64)           // 64 i-blocks
#define EOFF  (NSLAB * NPTS * ROWP) // float offset of E partials in ws
#define NEP   (NSLAB * NIB)         // 1024 E partials
#define REDF  (448 * RROW)          // reduction floats (7 waves x 64 rows)

typedef float v2f __attribute__((ext_vector_type(2)));
typedef float v4f __attribute__((ext_vector_type(4)));

// Pass 1: grid (64, 16) = 1024 blocks, block 512 = 8 waves, 4 blocks/CU
// -> 32 waves/CU = 8 waves/SIMD (if VGPR <= 64), the residency that gave the
// session's only high VALUBusy (R2: 76%). Same lean R12 loop: metric-folded
// i-row (dot = +cosh), no sigmoid / D_MIN branch / diag mask (validated),
// packed dot+acc from v4f subregisters. No unroll: single a0..a3 live range.
__global__ __launch_bounds__(512) void hydra_pair_kernel(
    const float* __restrict__ h, float* __restrict__ ws,
    float* __restrict__ out, const int use_ws) {
    const int tid   = threadIdx.x;
    const int lane  = tid & 63;
    const int wid   = tid >> 6;                 // 0..7
    const int i     = blockIdx.x * 64 + lane;
    const int jbase = blockIdx.y * JPB;

    __shared__ __align__(16) float lds[REDF + 16];   // 37.7 KB (tile overlaps)

    // coalesced stage of the 256-j tile (rows padded to ROWP)
    for (int idx = tid; idx < JPB * DIMP; idx += 512) {
        const int j = idx / DIMP;
        const int k = idx - j * DIMP;
        lds[j * ROWP + k] = h[jbase * DIMP + idx];
    }

    // metric-folded i-row, packed: nh = (t, -s) -> dot(nh, hj) = +cosh(d) = m
    v2f nhp[8];
    float nh16;
#pragma unroll
    for (int p = 0; p < 8; ++p) {
        const float s1 = (p == 0) ? 1.0f : -1.0f;
        nhp[p].x = s1 * h[i * DIMP + 2 * p];
        nhp[p].y = -h[i * DIMP + 2 * p + 1];
    }
    nh16 = -h[i * DIMP + 16];

    __syncthreads();

    v2f acp[8];
#pragma unroll
    for (int p = 0; p < 8; ++p) acp[p] = (v2f)(0.0f);
    float ac16 = 0.0f, sm = 0.0f, eacc = 0.0f;

    const float* rowp = lds + (wid * 32) * ROWP;
    for (int jj = 0; jj < 32; ++jj, rowp += ROWP) {
        const v4f a0 = ((const v4f*)rowp)[0];
        const v4f a1 = ((const v4f*)rowp)[1];
        const v4f a2 = ((const v4f*)rowp)[2];
        const v4f a3 = ((const v4f*)rowp)[3];
        const float a16 = rowp[16];

        // Lorentz dot (packed, 2 chains)
        v2f c0 = nhp[0] * a0.lo;
        v2f c1 = nhp[1] * a0.hi;
        c0 = __builtin_elementwise_fma(nhp[2], a1.lo, c0);
        c1 = __builtin_elementwise_fma(nhp[3], a1.hi, c1);
        c0 = __builtin_elementwise_fma(nhp[4], a2.lo, c0);
        c1 = __builtin_elementwise_fma(nhp[5], a2.hi, c1);
        c0 = __builtin_elementwise_fma(nhp[6], a3.lo, c0);
        c1 = __builtin_elementwise_fma(nhp[7], a3.hi, c1);
        const v2f cs = c0 + c1;
        const float m = fmaf(nh16, a16, cs.x + cs.y);        // cosh(d)

        // transform: m -> C = -dVdd * d / sinh(d); E += t - u; sm += C*m
        const float ss = fmaxf(fmaf(m, m, -1.0f), 2e-7f);    // sinh^2
        const float r  = __builtin_amdgcn_rsqf(ss);          // 1/sinh
        const float w  = ((m - 1.0f) - ss * r) + 1.0f;       // e^-d (>0 here)
        const float lg = __logf(w);                          // -d
        const float t  = __builtin_amdgcn_sqrtf(w);          // e^-d/2
        const float u  = w * w;                              // e^-2d
        const float K  = fmaf(0.5f, t, -(u + u));            // -dVdd
        const float C  = (K * r) * (-lg);                    // K*d/sinh
        eacc += (t - u);
        sm = fmaf(C, m, sm);

        const v2f Cs = {C, C};
        acp[0] = __builtin_elementwise_fma(Cs, a0.lo, acp[0]);
        acp[1] = __builtin_elementwise_fma(Cs, a0.hi, acp[1]);
        acp[2] = __builtin_elementwise_fma(Cs, a1.lo, acp[2]);
        acp[3] = __builtin_elementwise_fma(Cs, a1.hi, acp[3]);
        acp[4] = __builtin_elementwise_fma(Cs, a2.lo, acp[4]);
        acp[5] = __builtin_elementwise_fma(Cs, a2.hi, acp[5]);
        acp[6] = __builtin_elementwise_fma(Cs, a3.lo, acp[6]);
        acp[7] = __builtin_elementwise_fma(Cs, a3.hi, acp[7]);
        ac16 = fmaf(C, a16, ac16);
    }

    // F_i = ac - sm*h_i ; nh = (t, -s) so h_i[0] = nhp[0].x, h_i[k>=1] = -nh[k]
    float ac[DIMP];
    ac[0] = fmaf(-sm, nhp[0].x, acp[0].x);
    ac[1] = fmaf( sm, nhp[0].y, acp[0].y);
#pragma unroll
    for (int p = 1; p < 8; ++p) {
        ac[2 * p]     = fmaf(sm, nhp[p].x, acp[p].x);
        ac[2 * p + 1] = fmaf(sm, nhp[p].y, acp[p].y);
    }
    ac[16] = fmaf(sm, nh16, ac16);

#pragma unroll
    for (int off = 32; off > 0; off >>= 1) eacc += __shfl_xor(eacc, off);

    __syncthreads();   // tile reads done; reuse LDS for cross-wave reduction
    if (wid > 0) {
        float* dst = lds + ((wid - 1) * 64 + lane) * RROW;
#pragma unroll
        for (int k = 0; k < DIMP; ++k) dst[k] = ac[k];
        if (lane == 0) lds[REDF + wid] = eacc;
    }
    __syncthreads();

    if (wid == 0) {
        float esum = eacc;
#pragma unroll
        for (int q = 1; q < 8; ++q) esum += lds[REDF + q];
#pragma unroll
        for (int q = 0; q < 7; ++q) {
            const float* src = lds + (q * 64 + lane) * RROW;
#pragma unroll
            for (int k = 0; k < DIMP; ++k) ac[k] += src[k];
        }
        if (use_ws) {
            float* dst = ws + ((size_t)blockIdx.y * NPTS + i) * ROWP;
#pragma unroll
            for (int k = 0; k < DIMP; ++k) dst[k] = ac[k];
            if (lane == 0) ws[EOFF + blockIdx.y * NIB + blockIdx.x] = esum;
        } else {
#pragma unroll
            for (int k = 0; k < DIMP; ++k) atomicAdd(&out[i * DIMP + k], ac[k]);
            if (lane == 0) atomicAdd(&out[NPTS * DIMP], esum);
        }
    }
}

// Pass 2: grid 64 blocks x 256. lane -> i (64 per block), wid -> slab quarter.
__global__ __launch_bounds__(256) void hydra_finalize_kernel(
    const float* __restrict__ ws, float* __restrict__ out, const int use_ws) {
    const int tid  = threadIdx.x;
    const int lane = tid & 63;
    const int q    = tid >> 6;
    const int i    = blockIdx.x * 64 + lane;

    __shared__ __align__(16) float red[3 * 64 * RROW + 8];

    float v[DIMP];
#pragma unroll
    for (int k = 0; k < DIMP; ++k) v[k] = 0.0f;

    if (use_ws) {
#pragma unroll
        for (int ssl = 0; ssl < NSLAB / 4; ++ssl) {
            const int s = q * (NSLAB / 4) + ssl;
            const float* row = ws + ((size_t)s * NPTS + i) * ROWP;
            const v4f b0 = ((const v4f*)row)[0];
            const v4f b1 = ((const v4f*)row)[1];
            const v4f b2 = ((const v4f*)row)[2];
            const v4f b3 = ((const v4f*)row)[3];
            v[0]  += b0.x; v[1]  += b0.y; v[2]  += b0.z; v[3]  += b0.w;
            v[4]  += b1.x; v[5]  += b1.y; v[6]  += b1.z; v[7]  += b1.w;
            v[8]  += b2.x; v[9]  += b2.y; v[10] += b2.z; v[11] += b2.w;
            v[12] += b3.x; v[13] += b3.y; v[14] += b3.z; v[15] += b3.w;
            v[16] += row[16];
        }
        if (q > 0) {
            float* dst = red + ((q - 1) * 64 + lane) * RROW;
#pragma unroll
            for (int k = 0; k < DIMP; ++k) dst[k] = v[k];
        }
        __syncthreads();
        if (q == 0) {
#pragma unroll
            for (int qq = 0; qq < 3; ++qq) {
                const float* src = red + (qq * 64 + lane) * RROW;
#pragma unroll
                for (int k = 0; k < DIMP; ++k) v[k] += src[k];
            }
        }
    } else if (q == 0) {
#pragma unroll
        for (int k = 0; k < DIMP; ++k) v[k] = out[i * DIMP + k];
    }

    if (q == 0) {
        float ss = 0.0f;
#pragma unroll
        for (int k = 0; k < DIMP; ++k) ss = fmaf(v[k], v[k], ss);
        const float nrm   = sqrtf(ss);
        const float scale = fminf(6.0f / fmaxf(nrm, 1e-8f), 1.0f);
#pragma unroll
        for (int k = 0; k < DIMP; ++k) out[i * DIMP + k] = v[k] * scale;
    }

    if (blockIdx.x == 0) {
        if (use_ws) {
            float e = 0.0f;
#pragma unroll
            for (int t = 0; t < NEP / 256; ++t) e += ws[EOFF + tid + t * 256];
#pragma unroll
            for (int off = 32; off > 0; off >>= 1) e += __shfl_xor(e, off);
            __shared__ float es[4];
            if (lane == 0) es[q] = e;
            __syncthreads();
            if (tid == 0) out[NPTS * DIMP] = 0.5f * (es[0] + es[1] + es[2] + es[3]);
        } else {
            if (tid == 0) out[NPTS * DIMP] *= 0.5f;
        }
    }
}

extern "C" void kernel_launch(void* const* d_in, const int* in_sizes, int n_in,
                              void* d_out, int out_size, void* d_ws, size_t ws_size,
                              hipStream_t stream) {
    const float* h = (const float*)d_in[0];
    float* out = (float*)d_out;
    float* ws  = (float*)d_ws;

    const size_t need = (size_t)(EOFF + NEP) * sizeof(float);
    const int use_ws = (ws_size >= need) ? 1 : 0;
    if (!use_ws) {
        hipMemsetAsync(d_out, 0, (size_t)out_size * sizeof(float), stream);
    }

    dim3 grid(NIB, NSLAB);
    hydra_pair_kernel<<<grid, 512, 0, stream>>>(h, ws, out, use_ws);
    hydra_finalize_kernel<<<64, 256, 0, stream>>>(ws, out, use_ws);
}